// Round 4
// baseline (254.735 us; speedup 1.0000x reference)
//
#include <hip/hip_runtime.h>

// z_i = mu[a_i] + tril(cov[a_i]) @ eps_i
// B=4194304, A=64, D=8. Memory-bound: ~285 MB total traffic -> target ~50us.
//
// Design:
//  - Stage mu (64x8) and cov (64x8x8) in LDS once per block.
//  - Padded strides (65 / 9 floats per annotator) so the random per-lane
//    annotator gather spreads across banks: bank = (a*65 + k) % 32 = (a+k)%32
//    -> ~2 lanes/bank (free on CDNA4). Natural stride 64 would be a 64-way
//    same-bank conflict (64*a % 32 == 0).
//  - eps/z accessed as 2x float4 per row (32 B), coalesced.
//  - 2048 blocks x 256 threads, grid-stride x8: amortize staging, full occupancy
//    (LDS = ~19 KB/block, 8 blocks/CU by LDS -> 32 waves/CU).

#define THREADS 256
#define A_CNT 64
#define L_STRIDE 65   // 64 floats used + 1 pad
#define MU_STRIDE 9   // 8 floats used + 1 pad

__global__ __launch_bounds__(THREADS) void latent_rsample_kernel(
    const int* __restrict__ annot,
    const float* __restrict__ eps,
    const float* __restrict__ mu,
    const float* __restrict__ cov,
    float* __restrict__ out,
    int B)
{
    __shared__ float L_lds[A_CNT * L_STRIDE];
    __shared__ float mu_lds[A_CNT * MU_STRIDE];

    // Stage cov (full 8x8 per annotator; upper triangle never read) and mu.
    for (int e = threadIdx.x; e < A_CNT * 64; e += THREADS) {
        int a  = e >> 6;
        int rc = e & 63;
        L_lds[a * L_STRIDE + rc] = cov[e];
    }
    for (int e = threadIdx.x; e < A_CNT * 8; e += THREADS) {
        int a = e >> 3;
        int r = e & 7;
        mu_lds[a * MU_STRIDE + r] = mu[e];
    }
    __syncthreads();

    const int stride = gridDim.x * THREADS;
    for (int i = blockIdx.x * THREADS + threadIdx.x; i < B; i += stride) {
        const int a = annot[i];

        const float4* ep = reinterpret_cast<const float4*>(eps + (size_t)i * 8);
        const float4 e0 = ep[0];
        const float4 e1 = ep[1];
        const float e[8] = {e0.x, e0.y, e0.z, e0.w, e1.x, e1.y, e1.z, e1.w};

        const float* __restrict__ Lr = &L_lds[a * L_STRIDE];
        const float* __restrict__ mr = &mu_lds[a * MU_STRIDE];

        float z[8];
        #pragma unroll
        for (int r = 0; r < 8; ++r) {
            float acc = mr[r];
            #pragma unroll
            for (int c = 0; c <= r; ++c)      // tril: only c <= r contributes
                acc += Lr[r * 8 + c] * e[c];
            z[r] = acc;
        }

        float4* op = reinterpret_cast<float4*>(out + (size_t)i * 8);
        op[0] = make_float4(z[0], z[1], z[2], z[3]);
        op[1] = make_float4(z[4], z[5], z[6], z[7]);
    }
}

extern "C" void kernel_launch(void* const* d_in, const int* in_sizes, int n_in,
                              void* d_out, int out_size, void* d_ws, size_t ws_size,
                              hipStream_t stream) {
    const int*   annot = (const int*)  d_in[0];   // [B] int32
    const float* eps   = (const float*)d_in[1];   // [B, 8] f32
    const float* mu    = (const float*)d_in[2];   // [64, 8] f32
    const float* cov   = (const float*)d_in[3];   // [64, 8, 8] f32
    float* out = (float*)d_out;                   // [B, 8] f32

    const int B = in_sizes[0];                    // 4194304
    const int blocks = 2048;                      // grid-stride x8

    latent_rsample_kernel<<<blocks, THREADS, 0, stream>>>(annot, eps, mu, cov, out, B);
}